// Round 1
// baseline (194.400 us; speedup 1.0000x reference)
//
#include <hip/hip_runtime.h>
#include <math.h>

#define DIM 64
#define SEQ 784
#define BATCH 256

// ---------- cross-lane helpers (wave64 full reduction via DPP) ----------
template <int CTRL>
__device__ __forceinline__ float dpp_add_step(float s) {
    int v = __builtin_amdgcn_update_dpp(0, __float_as_int(s), CTRL, 0xF, 0xF, false);
    return s + __int_as_float(v);
}

// Sum across all 64 lanes; result broadcast (uniform, via readlane 63).
__device__ __forceinline__ float wave_allsum(float x) {
    x = dpp_add_step<0xB1>(x);   // quad_perm [1,0,3,2]  (xor 1)
    x = dpp_add_step<0x4E>(x);   // quad_perm [2,3,0,1]  (xor 2)
    x = dpp_add_step<0x141>(x);  // row_half_mirror      (pairs across quads)
    x = dpp_add_step<0x140>(x);  // row_mirror           (pairs across 8-groups)
    x = dpp_add_step<0x142>(x);  // row_bcast15          (16 -> 32)
    x = dpp_add_step<0x143>(x);  // row_bcast31          (32 -> 64, lane63 = total)
    return __int_as_float(__builtin_amdgcn_readlane(__float_as_int(x), 63));
}

__device__ __forceinline__ float gelu_exact(float v) {
    return 0.5f * v * (1.0f + erff(v * 0.70710678118654752440f));
}

// Wave-local LDS ordering: HW processes a wave's DS ops in order; the asm
// memory clobber stops the compiler reordering LDS accesses across it, and
// lgkmcnt(0) guarantees completion. Replaces block-wide __syncthreads for
// wave-private LDS buffers (avoids the s_barrier-implied vmcnt(0) drain).
__device__ __forceinline__ void wave_lds_fence() {
    asm volatile("s_waitcnt lgkmcnt(0)" ::: "memory");
}

// ---------- prepass: k[b,s,:] and alpha[b,s] for all rows ----------
// grid: 1024 blocks x 256 thr; each wave handles 49 consecutive rows
// (49 divides 784, so a wave never crosses a batch boundary).
// hbuf is wave-private -> no block barriers; wave fences only.
__global__ __launch_bounds__(256) void prepass_kernel(
    const float* __restrict__ x, const float* __restrict__ W_in,
    const float* __restrict__ pos_emb, const float* __restrict__ Wk,
    const float* __restrict__ Wb, const float* __restrict__ bbp,
    float* __restrict__ k_ws, float* __restrict__ alpha_ws)
{
    const int lane = threadIdx.x & 63;
    const int wv   = threadIdx.x >> 6;
    const int gw   = blockIdx.x * 4 + wv;     // 0..4095
    const int b    = gw >> 4;                 // /16
    const int s0   = (gw & 15) * 49;

    float4 wkr[16];
    const float4* wk4 = (const float4*)(Wk + lane * 64);  // lane owns Wk row `lane`
#pragma unroll
    for (int i = 0; i < 16; ++i) wkr[i] = wk4[i];
    const float win = W_in[lane];
    const float wb  = Wb[lane];
    const float bb  = bbp[0];

    __shared__ __align__(16) float hbuf[4][64];

    for (int r = 0; r < 49; ++r) {
        const int s = s0 + r;
        const float xs = x[b * SEQ + s];
        const float pe = pos_emb[s * 64 + lane];
        const float h  = gelu_exact(fmaf(xs, win, pe));
        const float bdot = wave_allsum(h * wb);
        wave_lds_fence();              // prior iteration's LDS reads complete
        hbuf[wv][lane] = h;
        wave_lds_fence();              // write visible to whole wave
        const float4* h4 = (const float4*)hbuf[wv];
        float kd = 0.f;
#pragma unroll
        for (int i = 0; i < 16; ++i) {
            float4 hv = h4[i];
            kd = fmaf(hv.x, wkr[i].x, kd);
            kd = fmaf(hv.y, wkr[i].y, kd);
            kd = fmaf(hv.z, wkr[i].z, kd);
            kd = fmaf(hv.w, wkr[i].w, kd);
        }
        float lam = wave_allsum(kd * kd);
        lam = fmaxf(lam, 1e-6f);
        const float beta = 1.0f / (1.0f + expf(-(bdot + bb)));
        const float al   = -expm1f(-beta * lam) / (lam + 1e-6f);
        const int row = b * SEQ + s;
        k_ws[row * 64 + lane] = kd;
        if (lane == 0) alpha_ws[row] = al;
    }
}

// ---------- shared epilogue (used by fused fallback only) ----------
__device__ __forceinline__ void epilogue(
    int b, int lane, float w, float* sh,
    const float* __restrict__ Wv, const float* __restrict__ ln_g,
    const float* __restrict__ ln_b, const float* __restrict__ Wc,
    const float* __restrict__ bc, float* __restrict__ out)
{
    __syncthreads();
    sh[lane] = w;
    __syncthreads();
    float last = 0.f;
    const float4* wv4 = (const float4*)(Wv + lane * 64);
    const float4* w4  = (const float4*)sh;
#pragma unroll
    for (int i = 0; i < 16; ++i) {
        float4 hv = w4[i], vv = wv4[i];
        last = fmaf(hv.x, vv.x, last);
        last = fmaf(hv.y, vv.y, last);
        last = fmaf(hv.z, vv.z, last);
        last = fmaf(hv.w, vv.w, last);
    }
    const float mu  = wave_allsum(last) * 0.015625f;
    const float dd  = last - mu;
    const float var = wave_allsum(dd * dd) * 0.015625f;
    const float ln  = dd / sqrtf(var + 1e-5f) * ln_g[lane] + ln_b[lane];
    __syncthreads();
    sh[lane] = ln;
    __syncthreads();
    if (lane < 10) {
        float acc = bc[lane];
        const float* wc = Wc + lane * 64;
#pragma unroll
        for (int j = 0; j < 64; ++j) acc = fmaf(wc[j], sh[j], acc);
        out[b * 10 + lane] = acc;
    }
}

// ---------- backward scan, a-sequence only: one wave per batch ----------
// Pair-Gram regroup (exact): for steps (t, t-1) with current u:
//   d0 = u.k_t ; e = u.k_{t-1} ; g = k_t.k_{t-1}   (3 independent reductions)
//   a_t = alpha_t*d0 ; d1 = e - a_t*g ; a_{t-1} = alpha_{t-1}*d1
//   u -= a_t*k_t + a_{t-1}*k_{t-1}
// a values parked in LDS during the loop (no global stores in steady state),
// written to alpha_ws (in place over alpha) once at the end.
__global__ __launch_bounds__(64) void scan_a_kernel(
    const float* __restrict__ x, const float* __restrict__ pos_emb,
    const float* __restrict__ W_in, const float* __restrict__ Wq,
    const float* __restrict__ k_ws, float* ab /* alpha in, a out */)
{
    const int lane = threadIdx.x;
    const int b    = blockIdx.x;
    __shared__ __align__(16) float sh[64];
    __shared__ __align__(16) float a_lds[SEQ];

    // u init: q at last position
    {
        const float h = gelu_exact(fmaf(x[b * SEQ + 783], W_in[lane], pos_emb[783 * 64 + lane]));
        sh[lane] = h;
    }
    wave_lds_fence();
    float u = 0.f;
    {
        const float4* wq4 = (const float4*)(Wq + lane * 64);
        const float4* h4  = (const float4*)sh;
#pragma unroll
        for (int i = 0; i < 16; ++i) {
            float4 hv = h4[i], qv = wq4[i];
            u = fmaf(hv.x, qv.x, u);
            u = fmaf(hv.y, qv.y, u);
            u = fmaf(hv.z, qv.z, u);
            u = fmaf(hv.w, qv.w, u);
        }
    }

    const float* kb  = k_ws + (size_t)b * SEQ * 64;
    float*       abp = ab + b * SEQ;

    float K0[16], A0[16], K1[16], A1[16], K2[16], A2[16];
    float aout[16];

#define LOADC(K, A, c)                                         \
    do {                                                       \
        const int tb_ = 783 - (c) * 16;                        \
        _Pragma("unroll")                                      \
        for (int i = 0; i < 16; ++i) {                         \
            K[i] = kb[(tb_ - i) * 64 + lane];                  \
            A[i] = abp[tb_ - i];                               \
        }                                                      \
    } while (0)

#define COMPC(K, A, c)                                         \
    do {                                                       \
        _Pragma("unroll")                                      \
        for (int g = 0; g < 8; ++g) {                          \
            const int i0 = 2 * g, i1 = 2 * g + 1;              \
            const float d0  = wave_allsum(u * K[i0]);          \
            const float e1  = wave_allsum(u * K[i1]);          \
            const float g01 = wave_allsum(K[i0] * K[i1]);      \
            const float a0  = A[i0] * d0;                      \
            const float d1  = fmaf(-a0, g01, e1);              \
            const float a1  = A[i1] * d1;                      \
            u = fmaf(-a0, K[i0], u);                           \
            u = fmaf(-a1, K[i1], u);                           \
            aout[i0] = a0; aout[i1] = a1;                      \
        }                                                      \
        if (lane == 0) {                                       \
            const int tb_ = 783 - (c) * 16;                    \
            _Pragma("unroll")                                  \
            for (int i = 0; i < 16; ++i)                       \
                a_lds[tb_ - i] = aout[i];                      \
        }                                                      \
    } while (0)

    // 3-deep prefetch, branch-free steady loop (49 chunks of 16 steps)
    LOADC(K0, A0, 0); LOADC(K1, A1, 1); LOADC(K2, A2, 2);
    for (int c = 0; c < 45; c += 3) {
        COMPC(K0, A0, c);     LOADC(K0, A0, c + 3);
        COMPC(K1, A1, c + 1); LOADC(K1, A1, c + 4);
        COMPC(K2, A2, c + 2); LOADC(K2, A2, c + 5);
    }
    COMPC(K0, A0, 45); LOADC(K0, A0, 48);
    COMPC(K1, A1, 46);
    COMPC(K2, A2, 47);
    COMPC(K0, A0, 48);
#undef LOADC
#undef COMPC

    // flush a-sequence to global (overwrites alpha_ws in place)
    wave_lds_fence();
#pragma unroll
    for (int j = 0; j < 13; ++j) {
        const int idx = j * 64 + lane;
        if (idx < SEQ) abp[idx] = a_lds[idx];
    }
}

// ---------- w accumulation + epilogue at high occupancy ----------
// grid: 256 blocks x 256 thr (4 waves). Block b: w = sum_t a_t * h_t,
// split 196 steps per wave, block-reduced; wave 0 runs the epilogue.
__global__ __launch_bounds__(256) void wsum_kernel(
    const float* __restrict__ x, const float* __restrict__ W_in,
    const float* __restrict__ pos_emb, const float* __restrict__ a_ws,
    const float* __restrict__ Wv, const float* __restrict__ ln_g,
    const float* __restrict__ ln_b, const float* __restrict__ Wc,
    const float* __restrict__ bc, float* __restrict__ out)
{
    const int lane = threadIdx.x & 63;
    const int wv   = threadIdx.x >> 6;
    const int b    = blockIdx.x;
    const float win = W_in[lane];
    const float* ap = a_ws + b * SEQ;
    const float* xp = x + b * SEQ;

    float w = 0.f;
    const int t0 = wv * 196;
#pragma unroll 4
    for (int i = 0; i < 196; ++i) {
        const int t = t0 + i;
        const float h = gelu_exact(fmaf(xp[t], win, pos_emb[t * 64 + lane]));
        w = fmaf(ap[t], h, w);
    }

    __shared__ __align__(16) float swr[4][64];
    __shared__ __align__(16) float sh[64];
    swr[wv][lane] = w;
    __syncthreads();
    if (wv != 0) return;

    w = swr[0][lane] + swr[1][lane] + swr[2][lane] + swr[3][lane];
    sh[lane] = w;
    wave_lds_fence();
    float last = 0.f;
    const float4* wv4 = (const float4*)(Wv + lane * 64);
    const float4* w4  = (const float4*)sh;
#pragma unroll
    for (int i = 0; i < 16; ++i) {
        float4 hv = w4[i], vv = wv4[i];
        last = fmaf(hv.x, vv.x, last);
        last = fmaf(hv.y, vv.y, last);
        last = fmaf(hv.z, vv.z, last);
        last = fmaf(hv.w, vv.w, last);
    }
    const float mu  = wave_allsum(last) * 0.015625f;
    const float dd  = last - mu;
    const float var = wave_allsum(dd * dd) * 0.015625f;
    const float ln  = dd / sqrtf(var + 1e-5f) * ln_g[lane] + ln_b[lane];
    wave_lds_fence();
    sh[lane] = ln;
    wave_lds_fence();
    if (lane < 10) {
        float acc = bc[lane];
        const float* wc = Wc + lane * 64;
#pragma unroll
        for (int j = 0; j < 64; ++j) acc = fmaf(wc[j], sh[j], acc);
        out[b * 10 + lane] = acc;
    }
}

// ---------- fused fallback (no workspace needed) ----------
__global__ __launch_bounds__(64) void fused_kernel(
    const float* __restrict__ x, const float* __restrict__ W_in,
    const float* __restrict__ pos_emb, const float* __restrict__ Wq,
    const float* __restrict__ Wk, const float* __restrict__ Wv,
    const float* __restrict__ Wb, const float* __restrict__ bbp,
    const float* __restrict__ ln_g, const float* __restrict__ ln_b,
    const float* __restrict__ Wc, const float* __restrict__ bc,
    float* __restrict__ out)
{
    const int lane = threadIdx.x;
    const int b    = blockIdx.x;
    __shared__ __align__(16) float sh[64];
    const float win = W_in[lane];
    const float wb  = Wb[lane];
    const float bb  = bbp[0];

    float4 wkr[16];
    const float4* wk4 = (const float4*)(Wk + lane * 64);
#pragma unroll
    for (int i = 0; i < 16; ++i) wkr[i] = wk4[i];

    float u;
    {
        const float h = gelu_exact(fmaf(x[b * SEQ + 783], win, pos_emb[783 * 64 + lane]));
        sh[lane] = h;
        __syncthreads();
        u = 0.f;
        const float4* wq4 = (const float4*)(Wq + lane * 64);
        const float4* h4  = (const float4*)sh;
#pragma unroll
        for (int i = 0; i < 16; ++i) {
            float4 hv = h4[i], qv = wq4[i];
            u = fmaf(hv.x, qv.x, u);
            u = fmaf(hv.y, qv.y, u);
            u = fmaf(hv.z, qv.z, u);
            u = fmaf(hv.w, qv.w, u);
        }
    }
    float w = 0.f;
    for (int t = 783; t >= 0; --t) {
        const float h = gelu_exact(fmaf(x[b * SEQ + t], win, pos_emb[t * 64 + lane]));
        const float bdot = wave_allsum(h * wb);
        __syncthreads();
        sh[lane] = h;
        __syncthreads();
        float kd = 0.f;
        const float4* h4 = (const float4*)sh;
#pragma unroll
        for (int i = 0; i < 16; ++i) {
            float4 hv = h4[i];
            kd = fmaf(hv.x, wkr[i].x, kd);
            kd = fmaf(hv.y, wkr[i].y, kd);
            kd = fmaf(hv.z, wkr[i].z, kd);
            kd = fmaf(hv.w, wkr[i].w, kd);
        }
        float lam = wave_allsum(kd * kd);
        lam = fmaxf(lam, 1e-6f);
        const float beta = 1.0f / (1.0f + expf(-(bdot + bb)));
        const float al   = -expm1f(-beta * lam) / (lam + 1e-6f);
        const float dot  = wave_allsum(u * kd);
        const float a    = al * dot;
        u = fmaf(-a, kd, u);
        w = fmaf(a, h, w);
    }
    epilogue(b, lane, w, sh, Wv, ln_g, ln_b, Wc, bc, out);
}

extern "C" void kernel_launch(void* const* d_in, const int* in_sizes, int n_in,
                              void* d_out, int out_size, void* d_ws, size_t ws_size,
                              hipStream_t stream)
{
    const float* x       = (const float*)d_in[0];
    const float* W_in    = (const float*)d_in[1];
    const float* pos_emb = (const float*)d_in[2];
    const float* Wq      = (const float*)d_in[3];
    const float* Wk      = (const float*)d_in[4];
    const float* Wv      = (const float*)d_in[5];
    const float* Wb      = (const float*)d_in[6];
    const float* bb      = (const float*)d_in[7];
    const float* ln_g    = (const float*)d_in[8];
    const float* ln_b    = (const float*)d_in[9];
    const float* Wc      = (const float*)d_in[10];
    const float* bc      = (const float*)d_in[11];
    float* out = (float*)d_out;

    const size_t k_elems = (size_t)BATCH * SEQ * 64;
    const size_t need = k_elems * sizeof(float) + (size_t)BATCH * SEQ * sizeof(float);

    if (ws_size >= need) {
        float* k_ws     = (float*)d_ws;
        float* alpha_ws = k_ws + k_elems;
        prepass_kernel<<<1024, 256, 0, stream>>>(x, W_in, pos_emb, Wk, Wb, bb, k_ws, alpha_ws);
        scan_a_kernel<<<BATCH, 64, 0, stream>>>(x, pos_emb, W_in, Wq, k_ws, alpha_ws);
        wsum_kernel<<<BATCH, 256, 0, stream>>>(x, W_in, pos_emb, alpha_ws, Wv, ln_g, ln_b,
                                               Wc, bc, out);
    } else {
        fused_kernel<<<BATCH, 64, 0, stream>>>(x, W_in, pos_emb, Wq, Wk, Wv, Wb, bb,
                                               ln_g, ln_b, Wc, bc, out);
    }
}

// Round 2
// 168.303 us; speedup vs baseline: 1.1551x; 1.1551x over previous
//
#include <hip/hip_runtime.h>
#include <math.h>

#define DIM 64
#define SEQ 784
#define BATCH 256

// ---------- cross-lane helpers (wave64 full reduction via DPP) ----------
template <int CTRL>
__device__ __forceinline__ float dpp_add_step(float s) {
    int v = __builtin_amdgcn_update_dpp(0, __float_as_int(s), CTRL, 0xF, 0xF, false);
    return s + __int_as_float(v);
}

// Sum across all 64 lanes; result broadcast (uniform, via readlane 63).
__device__ __forceinline__ float wave_allsum(float x) {
    x = dpp_add_step<0xB1>(x);   // quad_perm [1,0,3,2]  (xor 1)
    x = dpp_add_step<0x4E>(x);   // quad_perm [2,3,0,1]  (xor 2)
    x = dpp_add_step<0x141>(x);  // row_half_mirror      (pairs across quads)
    x = dpp_add_step<0x140>(x);  // row_mirror           (pairs across 8-groups)
    x = dpp_add_step<0x142>(x);  // row_bcast15          (16 -> 32)
    x = dpp_add_step<0x143>(x);  // row_bcast31          (32 -> 64, lane63 = total)
    return __int_as_float(__builtin_amdgcn_readlane(__float_as_int(x), 63));
}

__device__ __forceinline__ float gelu_exact(float v) {
    return 0.5f * v * (1.0f + erff(v * 0.70710678118654752440f));
}

// Wave-local LDS ordering (single-wave kernels only).
__device__ __forceinline__ void wave_lds_fence() {
    asm volatile("s_waitcnt lgkmcnt(0)" ::: "memory");
}

// ---------- prepass: k[b,s,:] and alpha[b,s] for all rows ----------
// REVERTED to the baseline __syncthreads version (known ~50 us in the
// 179 us run); the R1 fence variant is a regression suspect.
__global__ __launch_bounds__(256) void prepass_kernel(
    const float* __restrict__ x, const float* __restrict__ W_in,
    const float* __restrict__ pos_emb, const float* __restrict__ Wk,
    const float* __restrict__ Wb, const float* __restrict__ bbp,
    float* __restrict__ k_ws, float* __restrict__ alpha_ws)
{
    const int lane = threadIdx.x & 63;
    const int wv   = threadIdx.x >> 6;
    const int gw   = blockIdx.x * 4 + wv;     // 0..4095
    const int b    = gw >> 4;                 // /16
    const int s0   = (gw & 15) * 49;

    float4 wkr[16];
    const float4* wk4 = (const float4*)(Wk + lane * 64);  // lane owns Wk row `lane`
#pragma unroll
    for (int i = 0; i < 16; ++i) wkr[i] = wk4[i];
    const float win = W_in[lane];
    const float wb  = Wb[lane];
    const float bb  = bbp[0];

    __shared__ __align__(16) float hbuf[4][64];

    for (int r = 0; r < 49; ++r) {
        const int s = s0 + r;
        const float xs = x[b * SEQ + s];
        const float pe = pos_emb[s * 64 + lane];
        const float h  = gelu_exact(fmaf(xs, win, pe));
        const float bdot = wave_allsum(h * wb);
        __syncthreads();               // prior iteration's reads done
        hbuf[wv][lane] = h;
        __syncthreads();
        const float4* h4 = (const float4*)hbuf[wv];
        float kd = 0.f;
#pragma unroll
        for (int i = 0; i < 16; ++i) {
            float4 hv = h4[i];
            kd = fmaf(hv.x, wkr[i].x, kd);
            kd = fmaf(hv.y, wkr[i].y, kd);
            kd = fmaf(hv.z, wkr[i].z, kd);
            kd = fmaf(hv.w, wkr[i].w, kd);
        }
        float lam = wave_allsum(kd * kd);
        lam = fmaxf(lam, 1e-6f);
        const float beta = 1.0f / (1.0f + expf(-(bdot + bb)));
        const float al   = -expm1f(-beta * lam) / (lam + 1e-6f);
        const int row = b * SEQ + s;
        k_ws[row * 64 + lane] = kd;
        if (lane == 0) alpha_ws[row] = al;
    }
}

// ---------- shared epilogue (fused fallback only) ----------
__device__ __forceinline__ void epilogue(
    int b, int lane, float w, float* sh,
    const float* __restrict__ Wv, const float* __restrict__ ln_g,
    const float* __restrict__ ln_b, const float* __restrict__ Wc,
    const float* __restrict__ bc, float* __restrict__ out)
{
    __syncthreads();
    sh[lane] = w;
    __syncthreads();
    float last = 0.f;
    const float4* wv4 = (const float4*)(Wv + lane * 64);
    const float4* w4  = (const float4*)sh;
#pragma unroll
    for (int i = 0; i < 16; ++i) {
        float4 hv = w4[i], vv = wv4[i];
        last = fmaf(hv.x, vv.x, last);
        last = fmaf(hv.y, vv.y, last);
        last = fmaf(hv.z, vv.z, last);
        last = fmaf(hv.w, vv.w, last);
    }
    const float mu  = wave_allsum(last) * 0.015625f;
    const float dd  = last - mu;
    const float var = wave_allsum(dd * dd) * 0.015625f;
    const float ln  = dd / sqrtf(var + 1e-5f) * ln_g[lane] + ln_b[lane];
    __syncthreads();
    sh[lane] = ln;
    __syncthreads();
    if (lane < 10) {
        float acc = bc[lane];
        const float* wc = Wc + lane * 64;
#pragma unroll
        for (int j = 0; j < 64; ++j) acc = fmaf(wc[j], sh[j], acc);
        out[b * 10 + lane] = acc;
    }
}

// ---------- backward scan, a-sequence only: one wave per batch ----------
// Pair-Gram regroup (exact). Software pipeline pinned with sched_barrier(0)
// so the compiler cannot sink the prefetch loads to their uses (R1 failure:
// VGPR_Count=80 proved the 3 live chunks were collapsed). 20 VMEM loads per
// chunk (16 k + 4 uniform float4 for alpha), 3 chunks in flight = 60 <= 63
// vmcnt budget, so counted waits remain expressible.
__global__ __launch_bounds__(64) void scan_a_kernel(
    const float* __restrict__ x, const float* __restrict__ pos_emb,
    const float* __restrict__ W_in, const float* __restrict__ Wq,
    const float* __restrict__ k_ws, float* ab /* alpha in, a out */)
{
    const int lane = threadIdx.x;
    const int b    = blockIdx.x;
    __shared__ __align__(16) float sh[64];
    __shared__ __align__(16) float a_lds[SEQ];

    // u init: q at last position
    {
        const float h = gelu_exact(fmaf(x[b * SEQ + 783], W_in[lane], pos_emb[783 * 64 + lane]));
        sh[lane] = h;
    }
    wave_lds_fence();
    float u = 0.f;
    {
        const float4* wq4 = (const float4*)(Wq + lane * 64);
        const float4* h4  = (const float4*)sh;
#pragma unroll
        for (int i = 0; i < 16; ++i) {
            float4 hv = h4[i], qv = wq4[i];
            u = fmaf(hv.x, qv.x, u);
            u = fmaf(hv.y, qv.y, u);
            u = fmaf(hv.z, qv.z, u);
            u = fmaf(hv.w, qv.w, u);
        }
    }

    const float* kb  = k_ws + (size_t)b * SEQ * 64;
    float*       abp = ab + b * SEQ;

    float K0[16], A0[16], K1[16], A1[16], K2[16], A2[16];
    float aout[16];

#define SB __builtin_amdgcn_sched_barrier(0)

#define LOADC(K, A, c)                                         \
    do {                                                       \
        const int tb_ = 783 - (c) * 16;                        \
        _Pragma("unroll")                                      \
        for (int i = 0; i < 16; ++i)                           \
            K[i] = kb[(tb_ - i) * 64 + lane];                  \
        const float4* ap4 = (const float4*)&abp[tb_ - 15];     \
        _Pragma("unroll")                                      \
        for (int q = 0; q < 4; ++q) {                          \
            const float4 av = ap4[q];                          \
            A[15 - (q * 4 + 0)] = av.x;                        \
            A[15 - (q * 4 + 1)] = av.y;                        \
            A[15 - (q * 4 + 2)] = av.z;                        \
            A[15 - (q * 4 + 3)] = av.w;                        \
        }                                                      \
    } while (0)

#define COMPC(K, A, c)                                         \
    do {                                                       \
        _Pragma("unroll")                                      \
        for (int g = 0; g < 8; ++g) {                          \
            const int i0 = 2 * g, i1 = 2 * g + 1;              \
            const float d0  = wave_allsum(u * K[i0]);          \
            const float e1  = wave_allsum(u * K[i1]);          \
            const float g01 = wave_allsum(K[i0] * K[i1]);      \
            const float a0  = A[i0] * d0;                      \
            const float d1  = fmaf(-a0, g01, e1);              \
            const float a1  = A[i1] * d1;                      \
            u = fmaf(-a0, K[i0], u);                           \
            u = fmaf(-a1, K[i1], u);                           \
            aout[i0] = a0; aout[i1] = a1;                      \
        }                                                      \
        if (lane == 0) {                                       \
            const int tb_ = 783 - (c) * 16;                    \
            _Pragma("unroll")                                  \
            for (int i = 0; i < 16; ++i)                       \
                a_lds[tb_ - i] = aout[i];                      \
        }                                                      \
    } while (0)

    // 3-deep prefetch, schedule pinned at every macro boundary.
    LOADC(K0, A0, 0); SB;
    LOADC(K1, A1, 1); SB;
    LOADC(K2, A2, 2); SB;
    for (int c = 0; c < 45; c += 3) {
        COMPC(K0, A0, c);     SB; LOADC(K0, A0, c + 3); SB;
        COMPC(K1, A1, c + 1); SB; LOADC(K1, A1, c + 4); SB;
        COMPC(K2, A2, c + 2); SB; LOADC(K2, A2, c + 5); SB;
    }
    COMPC(K0, A0, 45); SB; LOADC(K0, A0, 48); SB;
    COMPC(K1, A1, 46); SB;
    COMPC(K2, A2, 47); SB;
    COMPC(K0, A0, 48);
#undef LOADC
#undef COMPC
#undef SB

    // flush a-sequence to global (overwrites alpha_ws in place)
    wave_lds_fence();
#pragma unroll
    for (int j = 0; j < 13; ++j) {
        const int idx = j * 64 + lane;
        if (idx < SEQ) abp[idx] = a_lds[idx];
    }
}

// ---------- w accumulation + epilogue at higher occupancy ----------
// grid: 256 blocks x 512 thr (8 waves -> 2 waves/SIMD). Block b:
// w = sum_t a_t * h_t, 98 steps per wave, block-reduced; wave 0 epilogue.
__global__ __launch_bounds__(512) void wsum_kernel(
    const float* __restrict__ x, const float* __restrict__ W_in,
    const float* __restrict__ pos_emb, const float* __restrict__ a_ws,
    const float* __restrict__ Wv, const float* __restrict__ ln_g,
    const float* __restrict__ ln_b, const float* __restrict__ Wc,
    const float* __restrict__ bc, float* __restrict__ out)
{
    const int lane = threadIdx.x & 63;
    const int wv   = threadIdx.x >> 6;        // 0..7
    const int b    = blockIdx.x;
    const float win = W_in[lane];
    const float* ap = a_ws + b * SEQ;
    const float* xp = x + b * SEQ;

    float w = 0.f;
    const int t0 = wv * 98;
#pragma unroll 2
    for (int i = 0; i < 98; ++i) {
        const int t = t0 + i;
        const float h = gelu_exact(fmaf(xp[t], win, pos_emb[t * 64 + lane]));
        w = fmaf(ap[t], h, w);
    }

    __shared__ __align__(16) float swr[8][64];
    __shared__ __align__(16) float sh[64];
    swr[wv][lane] = w;
    __syncthreads();
    if (wv != 0) return;

    w = swr[0][lane] + swr[1][lane] + swr[2][lane] + swr[3][lane]
      + swr[4][lane] + swr[5][lane] + swr[6][lane] + swr[7][lane];
    sh[lane] = w;
    wave_lds_fence();
    float last = 0.f;
    const float4* wv4 = (const float4*)(Wv + lane * 64);
    const float4* w4  = (const float4*)sh;
#pragma unroll
    for (int i = 0; i < 16; ++i) {
        float4 hv = w4[i], vv = wv4[i];
        last = fmaf(hv.x, vv.x, last);
        last = fmaf(hv.y, vv.y, last);
        last = fmaf(hv.z, vv.z, last);
        last = fmaf(hv.w, vv.w, last);
    }
    const float mu  = wave_allsum(last) * 0.015625f;
    const float dd  = last - mu;
    const float var = wave_allsum(dd * dd) * 0.015625f;
    const float ln  = dd / sqrtf(var + 1e-5f) * ln_g[lane] + ln_b[lane];
    wave_lds_fence();
    sh[lane] = ln;
    wave_lds_fence();
    if (lane < 10) {
        float acc = bc[lane];
        const float* wc = Wc + lane * 64;
#pragma unroll
        for (int j = 0; j < 64; ++j) acc = fmaf(wc[j], sh[j], acc);
        out[b * 10 + lane] = acc;
    }
}

// ---------- fused fallback (no workspace needed) ----------
__global__ __launch_bounds__(64) void fused_kernel(
    const float* __restrict__ x, const float* __restrict__ W_in,
    const float* __restrict__ pos_emb, const float* __restrict__ Wq,
    const float* __restrict__ Wk, const float* __restrict__ Wv,
    const float* __restrict__ Wb, const float* __restrict__ bbp,
    const float* __restrict__ ln_g, const float* __restrict__ ln_b,
    const float* __restrict__ Wc, const float* __restrict__ bc,
    float* __restrict__ out)
{
    const int lane = threadIdx.x;
    const int b    = blockIdx.x;
    __shared__ __align__(16) float sh[64];
    const float win = W_in[lane];
    const float wb  = Wb[lane];
    const float bb  = bbp[0];

    float4 wkr[16];
    const float4* wk4 = (const float4*)(Wk + lane * 64);
#pragma unroll
    for (int i = 0; i < 16; ++i) wkr[i] = wk4[i];

    float u;
    {
        const float h = gelu_exact(fmaf(x[b * SEQ + 783], win, pos_emb[783 * 64 + lane]));
        sh[lane] = h;
        __syncthreads();
        u = 0.f;
        const float4* wq4 = (const float4*)(Wq + lane * 64);
        const float4* h4  = (const float4*)sh;
#pragma unroll
        for (int i = 0; i < 16; ++i) {
            float4 hv = h4[i], qv = wq4[i];
            u = fmaf(hv.x, qv.x, u);
            u = fmaf(hv.y, qv.y, u);
            u = fmaf(hv.z, qv.z, u);
            u = fmaf(hv.w, qv.w, u);
        }
    }
    float w = 0.f;
    for (int t = 783; t >= 0; --t) {
        const float h = gelu_exact(fmaf(x[b * SEQ + t], win, pos_emb[t * 64 + lane]));
        const float bdot = wave_allsum(h * wb);
        __syncthreads();
        sh[lane] = h;
        __syncthreads();
        float kd = 0.f;
        const float4* h4 = (const float4*)sh;
#pragma unroll
        for (int i = 0; i < 16; ++i) {
            float4 hv = h4[i];
            kd = fmaf(hv.x, wkr[i].x, kd);
            kd = fmaf(hv.y, wkr[i].y, kd);
            kd = fmaf(hv.z, wkr[i].z, kd);
            kd = fmaf(hv.w, wkr[i].w, kd);
        }
        float lam = wave_allsum(kd * kd);
        lam = fmaxf(lam, 1e-6f);
        const float beta = 1.0f / (1.0f + expf(-(bdot + bb)));
        const float al   = -expm1f(-beta * lam) / (lam + 1e-6f);
        const float dot  = wave_allsum(u * kd);
        const float a    = al * dot;
        u = fmaf(-a, kd, u);
        w = fmaf(a, h, w);
    }
    epilogue(b, lane, w, sh, Wv, ln_g, ln_b, Wc, bc, out);
}

extern "C" void kernel_launch(void* const* d_in, const int* in_sizes, int n_in,
                              void* d_out, int out_size, void* d_ws, size_t ws_size,
                              hipStream_t stream)
{
    const float* x       = (const float*)d_in[0];
    const float* W_in    = (const float*)d_in[1];
    const float* pos_emb = (const float*)d_in[2];
    const float* Wq      = (const float*)d_in[3];
    const float* Wk      = (const float*)d_in[4];
    const float* Wv      = (const float*)d_in[5];
    const float* Wb      = (const float*)d_in[6];
    const float* bb      = (const float*)d_in[7];
    const float* ln_g    = (const float*)d_in[8];
    const float* ln_b    = (const float*)d_in[9];
    const float* Wc      = (const float*)d_in[10];
    const float* bc      = (const float*)d_in[11];
    float* out = (float*)d_out;

    const size_t k_elems = (size_t)BATCH * SEQ * 64;
    const size_t need = k_elems * sizeof(float) + (size_t)BATCH * SEQ * sizeof(float);

    if (ws_size >= need) {
        float* k_ws     = (float*)d_ws;
        float* alpha_ws = k_ws + k_elems;
        prepass_kernel<<<1024, 256, 0, stream>>>(x, W_in, pos_emb, Wk, Wb, bb, k_ws, alpha_ws);
        scan_a_kernel<<<BATCH, 64, 0, stream>>>(x, pos_emb, W_in, Wq, k_ws, alpha_ws);
        wsum_kernel<<<BATCH, 512, 0, stream>>>(x, W_in, pos_emb, alpha_ws, Wv, ln_g, ln_b,
                                               Wc, bc, out);
    } else {
        fused_kernel<<<BATCH, 64, 0, stream>>>(x, W_in, pos_emb, Wq, Wk, Wv, Wb, bb,
                                               ln_g, ln_b, Wc, bc, out);
    }
}